// Round 7
// baseline (585.803 us; speedup 1.0000x reference)
//
#include <hip/hip_runtime.h>
#include <math.h>

#define HH 4096
#define OO 4096
#define MAXLEN 2048

typedef float f4 __attribute__((ext_vector_type(4)));

__device__ inline float wave_sum(float v) {
#pragma unroll
    for (int off = 32; off; off >>= 1) v += __shfl_down(v, off, 64);
    return v;
}
__device__ inline float wave_max(float v) {
#pragma unroll
    for (int off = 32; off; off >>= 1) v = fmaxf(v, __shfl_down(v, off, 64));
    return v;
}

// sum 256 per-thread partials; result valid in all threads
__device__ inline float block_sum(float acc) {
    __shared__ float red[4];
    acc = wave_sum(acc);
    int t = threadIdx.x;
    if ((t & 63) == 0) red[t >> 6] = acc;
    __syncthreads();
    return red[0] + red[1] + red[2] + red[3];
}

// per-thread partial dot over 1024*NV floats; 256 threads/block.
// NT: non-temporal (stream-once) hint on the W side only.
template <int NV, bool NT>
__device__ inline float dot_row(const f4* __restrict__ W4, const f4* __restrict__ x4) {
    int t = threadIdx.x;
    float acc = 0.f;
#pragma unroll
    for (int j = 0; j < NV; ++j) {
        f4 w = NT ? __builtin_nontemporal_load(W4 + t + 256 * j) : W4[t + 256 * j];
        f4 v = x4[t + 256 * j];
        acc = fmaf(w[0], v[0], acc);
        acc = fmaf(w[1], v[1], acc);
        acc = fmaf(w[2], v[2], acc);
        acc = fmaf(w[3], v[3], acc);
    }
    return acc;
}

// fused first stage: blocks 0..2047 -> attention logits (att_W nt, L=8192)
//                    blocks 2048..14335 -> gh[r] = W_hh[r,:]·h + b_hh[r] (non-nt)
// block 0 thread 0 also zeroes the two ticket counters used downstream.
__global__ void k_stage1(const float* __restrict__ att_W, const float* __restrict__ att_b,
                         const float* __restrict__ emb_W, const int* __restrict__ idx,
                         const float* __restrict__ hidden,
                         const float* __restrict__ W_hh, const float* __restrict__ b_hh,
                         float* __restrict__ attlog, float* __restrict__ gh,
                         unsigned int* __restrict__ counters) {
    int blk = blockIdx.x;
    if (blk == 0 && threadIdx.x == 0) { counters[0] = 0; counters[1] = 0; }
    if (blk < MAXLEN) {
        const float* emb = emb_W + (size_t)idx[0] * HH;
        const float* Wr = att_W + (size_t)blk * (2 * HH);
        float acc = dot_row<4, true>((const f4*)Wr, (const f4*)emb)
                  + dot_row<4, true>((const f4*)(Wr + HH), (const f4*)hidden);
        float tot = block_sum(acc);
        if (threadIdx.x == 0) attlog[blk] = tot + att_b[blk];
    } else {
        int r = blk - MAXLEN;
        float acc = dot_row<4, false>((const f4*)(W_hh + (size_t)r * HH), (const f4*)hidden);
        float tot = block_sum(acc);
        if (threadIdx.x == 0) gh[r] = tot + b_hh[r];
    }
}

// fused softmax + weighted partial column-sums + folded final reduce.
// 512 blocks = 128 row-chunks (16 rows) x 4 col-quarters; q==0 blocks write atw.
// The block drawing the last ticket reduces part -> atap (deterministic order).
__global__ void k_smpart(const float* __restrict__ attlog, const float* __restrict__ E,
                         float* __restrict__ part, float* __restrict__ atw,
                         float* __restrict__ atap, unsigned int* __restrict__ counters) {
    __shared__ float red[4];
    __shared__ float s_mx, s_sum;
    __shared__ unsigned int s_ticket;
    int t = threadIdx.x;
    int q = blockIdx.x & 3;
    int c = blockIdx.x >> 2;              // 0..127

    float v[8];
    float m = -INFINITY;
#pragma unroll
    for (int j = 0; j < 8; ++j) { v[j] = attlog[t + 256 * j]; m = fmaxf(m, v[j]); }
    m = wave_max(m);
    if ((t & 63) == 0) red[t >> 6] = m;
    __syncthreads();
    if (t == 0) s_mx = fmaxf(fmaxf(red[0], red[1]), fmaxf(red[2], red[3]));
    __syncthreads();
    float mx = s_mx;
    float s = 0.f;
#pragma unroll
    for (int j = 0; j < 8; ++j) s += expf(v[j] - mx);
    s = wave_sum(s);
    __syncthreads();
    if ((t & 63) == 0) red[t >> 6] = s;
    __syncthreads();
    if (t == 0) s_sum = red[0] + red[1] + red[2] + red[3];
    __syncthreads();
    float inv = 1.0f / s_sum;

    int col4 = q * 256 + t;
    f4 acc = {0.f, 0.f, 0.f, 0.f};
#pragma unroll 8
    for (int rr = 0; rr < 16; ++rr) {
        int mrow = c * 16 + rr;
        float wm = expf(attlog[mrow] - mx) * inv;
        f4 e = __builtin_nontemporal_load((const f4*)(E + (size_t)mrow * HH) + col4);
        acc[0] = fmaf(wm, e[0], acc[0]);
        acc[1] = fmaf(wm, e[1], acc[1]);
        acc[2] = fmaf(wm, e[2], acc[2]);
        acc[3] = fmaf(wm, e[3], acc[3]);
    }
    ((f4*)(part + (size_t)c * HH))[col4] = acc;

    if (q == 0 && t < 16) {
        int mrow = c * 16 + t;
        atw[mrow] = expf(attlog[mrow] - mx) * inv;
    }

    // ---- folded reduce: last-finishing block sums 128 partial rows -> atap
    __threadfence();                       // make part-writes device-visible
    __syncthreads();
    if (t == 0) s_ticket = atomicAdd(&counters[0], 1u);
    __syncthreads();
    if (s_ticket == 511u) {
        __threadfence();                   // acquire: see all part writes
        for (int j4 = t; j4 < HH / 4; j4 += 256) {
            f4 ssum = {0.f, 0.f, 0.f, 0.f};
#pragma unroll 8
            for (int cc = 0; cc < 128; ++cc) {
                f4 p = ((const f4*)(part + (size_t)cc * HH))[j4];
                ssum[0] += p[0]; ssum[1] += p[1]; ssum[2] += p[2]; ssum[3] += p[3];
            }
            ((f4*)atap)[j4] = ssum;
        }
    }
}

// x = relu(atc_W @ [emb | atap] + atc_b), block per row; atc_W stream-once
__global__ void k_atc(const float* __restrict__ atc_W, const float* __restrict__ atc_b,
                      const float* __restrict__ emb_W, const int* __restrict__ idx,
                      const float* __restrict__ atap, float* __restrict__ x) {
    int r = blockIdx.x;
    const float* emb = emb_W + (size_t)idx[0] * HH;
    const float* Wr = atc_W + (size_t)r * (2 * HH);
    float acc = dot_row<4, true>((const f4*)Wr, (const f4*)emb)
              + dot_row<4, true>((const f4*)(Wr + HH), (const f4*)atap);
    float tot = block_sum(acc);
    if (threadIdx.x == 0) x[r] = fmaxf(tot + atc_b[r], 0.f);
}

// gi + gate math: block r computes 3 W_ih row-dots vs x (nt), combines with
// precomputed gh (already includes b_hh) -> h_new[r].
__global__ void k_gig(const float* __restrict__ W_ih, const float* __restrict__ b_ih,
                      const float* __restrict__ x, const float* __restrict__ gh,
                      const float* __restrict__ h, float* __restrict__ h_new) {
    __shared__ float red[3][4];
    int r = blockIdx.x;
    int t = threadIdx.x, wid = t >> 6, lane = t & 63;
    const f4* xv = (const f4*)x;
    float a[3];
    a[0] = dot_row<4, true>((const f4*)(W_ih + (size_t)r * HH), xv);
    a[1] = dot_row<4, true>((const f4*)(W_ih + (size_t)(HH + r) * HH), xv);
    a[2] = dot_row<4, true>((const f4*)(W_ih + (size_t)(2 * HH + r) * HH), xv);
#pragma unroll
    for (int k = 0; k < 3; ++k) {
        float s = wave_sum(a[k]);
        if (lane == 0) red[k][wid] = s;
    }
    __syncthreads();
    if (t == 0) {
        float i_r = red[0][0] + red[0][1] + red[0][2] + red[0][3] + b_ih[r];
        float i_z = red[1][0] + red[1][1] + red[1][2] + red[1][3] + b_ih[HH + r];
        float i_n = red[2][0] + red[2][1] + red[2][2] + red[2][3] + b_ih[2 * HH + r];
        float h_r = gh[r];
        float h_z = gh[HH + r];
        float h_n = gh[2 * HH + r];
        float rg = 1.f / (1.f + expf(-(i_r + h_r)));
        float z  = 1.f / (1.f + expf(-(i_z + h_z)));
        float n  = tanhf(i_n + rg * h_n);
        h_new[r] = (1.f - z) * n + z * h[r];
    }
}

// out logits (block per row, out_W NON-nt: L3-residency candidate with W_hh)
// + folded log_softmax: the block drawing the final ticket computes it.
__global__ void k_out(const float* __restrict__ W, const float* __restrict__ xv,
                      const float* __restrict__ b, float* __restrict__ outlog,
                      float* __restrict__ out, unsigned int* __restrict__ counters) {
    __shared__ unsigned int s_ticket;
    int r = blockIdx.x;
    int t = threadIdx.x;
    float acc = dot_row<4, false>((const f4*)(W + (size_t)r * HH), (const f4*)xv);
    float tot = block_sum(acc);
    if (t == 0) outlog[r] = tot + b[r];

    __threadfence();
    __syncthreads();
    if (t == 0) s_ticket = atomicAdd(&counters[1], 1u);
    __syncthreads();
    if (s_ticket == (unsigned)(HH - 1)) {
        __threadfence();                   // acquire: see all outlog writes
        __shared__ float red[4];
        __shared__ float bval;
        float v[16];
        float m = -INFINITY;
#pragma unroll
        for (int j = 0; j < 16; ++j) { v[j] = outlog[t + 256 * j]; m = fmaxf(m, v[j]); }
        m = wave_max(m);
        if ((t & 63) == 0) red[t >> 6] = m;
        __syncthreads();
        if (t == 0) bval = fmaxf(fmaxf(red[0], red[1]), fmaxf(red[2], red[3]));
        __syncthreads();
        float mx = bval;
        float s = 0.f;
#pragma unroll
        for (int j = 0; j < 16; ++j) s += expf(v[j] - mx);
        s = wave_sum(s);
        __syncthreads();
        if ((t & 63) == 0) red[t >> 6] = s;
        __syncthreads();
        if (t == 0) bval = red[0] + red[1] + red[2] + red[3];
        __syncthreads();
        float lse = mx + logf(bval);
#pragma unroll
        for (int j = 0; j < 16; ++j) out[t + 256 * j] = v[j] - lse;
    }
}

extern "C" void kernel_launch(void* const* d_in, const int* in_sizes, int n_in,
                              void* d_out, int out_size, void* d_ws, size_t ws_size,
                              hipStream_t stream) {
    const int*   idx     = (const int*)  d_in[0];
    const float* hidden  = (const float*)d_in[1];
    // d_in[2] (encoder_output) unused by the forward pass
    const float* enc     = (const float*)d_in[3];
    const float* emb_W   = (const float*)d_in[4];
    const float* att_W   = (const float*)d_in[5];
    const float* att_b   = (const float*)d_in[6];
    const float* atc_W   = (const float*)d_in[7];
    const float* atc_b   = (const float*)d_in[8];
    const float* W_ih    = (const float*)d_in[9];
    const float* W_hh    = (const float*)d_in[10];
    const float* b_ih    = (const float*)d_in[11];
    const float* b_hh    = (const float*)d_in[12];
    const float* out_W   = (const float*)d_in[13];
    const float* out_b   = (const float*)d_in[14];

    float* out    = (float*)d_out;        // [0, 4096)    log_softmax
    float* h_new  = out + OO;             // [4096, 8192) new hidden
    float* atw    = out + OO + HH;        // [8192,10240) attention weights

    float* ws         = (float*)d_ws;
    float* attlog     = ws;               // 2048
    float* atap       = ws + 2048;        // 4096
    float* x          = ws + 6144;        // 4096
    float* outlog     = ws + 10240;       // 4096
    float* gh         = ws + 14336;       // 12288
    float* part       = ws + 26624;       // 128*4096
    unsigned int* counters = (unsigned int*)(ws + 26624 + 128 * HH); // 2 u32

    // 1. att logits + gh = W_hh@hidden + b_hh (fused); zeroes ticket counters
    k_stage1<<<MAXLEN + 3 * HH, 256, 0, stream>>>(att_W, att_b, emb_W, idx, hidden,
                                                  W_hh, b_hh, attlog, gh, counters);
    // 2. softmax + weighted partials + folded reduce -> atap (writes atw output)
    k_smpart<<<512, 256, 0, stream>>>(attlog, enc, part, atw, atap, counters);
    // 3. x = relu(atc_W @ [emb|atap] + atc_b)
    k_atc<<<HH, 256, 0, stream>>>(atc_W, atc_b, emb_W, idx, atap, x);
    // 4. gi + gate math -> h_new output
    k_gig<<<HH, 256, 0, stream>>>(W_ih, b_ih, x, gh, hidden, h_new);
    // 5. out logits + folded log_softmax -> out
    k_out<<<HH, 256, 0, stream>>>(out_W, h_new, out_b, outlog, out, counters);
}

// Round 8
// 128.629 us; speedup vs baseline: 4.5542x; 4.5542x over previous
//
#include <hip/hip_runtime.h>
#include <math.h>

#define HH 4096
#define OO 4096
#define MAXLEN 2048

typedef float f4 __attribute__((ext_vector_type(4)));

__device__ inline float wave_sum(float v) {
#pragma unroll
    for (int off = 32; off; off >>= 1) v += __shfl_down(v, off, 64);
    return v;
}
__device__ inline float wave_max(float v) {
#pragma unroll
    for (int off = 32; off; off >>= 1) v = fmaxf(v, __shfl_down(v, off, 64));
    return v;
}

// sum 256 per-thread partials; result valid in all threads
__device__ inline float block_sum(float acc) {
    __shared__ float red[4];
    acc = wave_sum(acc);
    int t = threadIdx.x;
    if ((t & 63) == 0) red[t >> 6] = acc;
    __syncthreads();
    return red[0] + red[1] + red[2] + red[3];
}

// per-thread partial dot over 1024*NV floats; 256 threads/block.
// NT: non-temporal (stream-once) hint on the W side only.
template <int NV, bool NT>
__device__ inline float dot_row(const f4* __restrict__ W4, const f4* __restrict__ x4) {
    int t = threadIdx.x;
    float acc = 0.f;
#pragma unroll
    for (int j = 0; j < NV; ++j) {
        f4 w = NT ? __builtin_nontemporal_load(W4 + t + 256 * j) : W4[t + 256 * j];
        f4 v = x4[t + 256 * j];
        acc = fmaf(w[0], v[0], acc);
        acc = fmaf(w[1], v[1], acc);
        acc = fmaf(w[2], v[2], acc);
        acc = fmaf(w[3], v[3], acc);
    }
    return acc;
}

// fused first stage, 14336 = 7*2048 blocks, interleaved:
//   blk%7==0 -> attention logit row blk/7   (att_W nt, L=8192, 2 passes)
//   else     -> gh row = blk - blk/7 - 1    (W_hh non-nt = L3-resident, 1 pass)
__global__ void k_stage1(const float* __restrict__ att_W, const float* __restrict__ att_b,
                         const float* __restrict__ emb_W, const int* __restrict__ idx,
                         const float* __restrict__ hidden,
                         const float* __restrict__ W_hh, const float* __restrict__ b_hh,
                         float* __restrict__ attlog, float* __restrict__ gh) {
    int blk = blockIdx.x;
    int k = blk / 7;
    if (blk % 7 == 0) {
        int r = k;                         // 0..2047
        const float* emb = emb_W + (size_t)idx[0] * HH;
        const float* Wr = att_W + (size_t)r * (2 * HH);
        float acc = dot_row<4, true>((const f4*)Wr, (const f4*)emb)
                  + dot_row<4, true>((const f4*)(Wr + HH), (const f4*)hidden);
        float tot = block_sum(acc);
        if (threadIdx.x == 0) attlog[r] = tot + att_b[r];
    } else {
        int r = blk - k - 1;               // 0..12287, bijective
        float acc = dot_row<4, false>((const f4*)(W_hh + (size_t)r * HH), (const f4*)hidden);
        float tot = block_sum(acc);
        if (threadIdx.x == 0) gh[r] = tot + b_hh[r];
    }
}

// fused softmax + weighted partial column-sums.
// 512 blocks = 128 row-chunks (16 rows) x 4 col-quarters. Each block
// redundantly computes softmax stats from attlog (8KB, cache-resident).
// q==0 blocks also write atw (the third output). enc NON-nt (L3-resident set).
__global__ void k_smpart(const float* __restrict__ attlog, const float* __restrict__ E,
                         float* __restrict__ part, float* __restrict__ atw) {
    __shared__ float red[4];
    __shared__ float s_mx, s_sum;
    int t = threadIdx.x;
    int q = blockIdx.x & 3;
    int c = blockIdx.x >> 2;              // 0..127

    float v[8];
    float m = -INFINITY;
#pragma unroll
    for (int j = 0; j < 8; ++j) { v[j] = attlog[t + 256 * j]; m = fmaxf(m, v[j]); }
    m = wave_max(m);
    if ((t & 63) == 0) red[t >> 6] = m;
    __syncthreads();
    if (t == 0) s_mx = fmaxf(fmaxf(red[0], red[1]), fmaxf(red[2], red[3]));
    __syncthreads();
    float mx = s_mx;
    float s = 0.f;
#pragma unroll
    for (int j = 0; j < 8; ++j) s += expf(v[j] - mx);
    s = wave_sum(s);
    __syncthreads();
    if ((t & 63) == 0) red[t >> 6] = s;
    __syncthreads();
    if (t == 0) s_sum = red[0] + red[1] + red[2] + red[3];
    __syncthreads();
    float inv = 1.0f / s_sum;

    int col4 = q * 256 + t;
    f4 acc = {0.f, 0.f, 0.f, 0.f};
#pragma unroll 8
    for (int rr = 0; rr < 16; ++rr) {
        int mrow = c * 16 + rr;
        float wm = expf(attlog[mrow] - mx) * inv;
        f4 e = ((const f4*)(E + (size_t)mrow * HH))[col4];
        acc[0] = fmaf(wm, e[0], acc[0]);
        acc[1] = fmaf(wm, e[1], acc[1]);
        acc[2] = fmaf(wm, e[2], acc[2]);
        acc[3] = fmaf(wm, e[3], acc[3]);
    }
    ((f4*)(part + (size_t)c * HH))[col4] = acc;

    if (q == 0 && t < 16) {
        int mrow = c * 16 + t;
        atw[mrow] = expf(attlog[mrow] - mx) * inv;
    }
}

// deterministic reduce of 128 partial rows -> atap (part is L2-resident)
__global__ void k_red(const float* __restrict__ part, float* __restrict__ atap) {
    int j = blockIdx.x * 256 + threadIdx.x;
    float s = 0.f;
#pragma unroll 8
    for (int c = 0; c < 128; ++c) s += part[(size_t)c * HH + j];
    atap[j] = s;
}

// x = relu(atc_W @ [emb | atap] + atc_b), block per row; atc_W stream-once
__global__ void k_atc(const float* __restrict__ atc_W, const float* __restrict__ atc_b,
                      const float* __restrict__ emb_W, const int* __restrict__ idx,
                      const float* __restrict__ atap, float* __restrict__ x) {
    int r = blockIdx.x;
    const float* emb = emb_W + (size_t)idx[0] * HH;
    const float* Wr = atc_W + (size_t)r * (2 * HH);
    float acc = dot_row<4, true>((const f4*)Wr, (const f4*)emb)
              + dot_row<4, true>((const f4*)(Wr + HH), (const f4*)atap);
    float tot = block_sum(acc);
    if (threadIdx.x == 0) x[r] = fmaxf(tot + atc_b[r], 0.f);
}

// gi + gate math: block r computes 3 W_ih row-dots vs x (nt), combines with
// precomputed gh (already includes b_hh) -> h_new[r].
__global__ void k_gig(const float* __restrict__ W_ih, const float* __restrict__ b_ih,
                      const float* __restrict__ x, const float* __restrict__ gh,
                      const float* __restrict__ h, float* __restrict__ h_new) {
    __shared__ float red[3][4];
    int r = blockIdx.x;
    int t = threadIdx.x, wid = t >> 6, lane = t & 63;
    const f4* xv = (const f4*)x;
    float a[3];
    a[0] = dot_row<4, true>((const f4*)(W_ih + (size_t)r * HH), xv);
    a[1] = dot_row<4, true>((const f4*)(W_ih + (size_t)(HH + r) * HH), xv);
    a[2] = dot_row<4, true>((const f4*)(W_ih + (size_t)(2 * HH + r) * HH), xv);
#pragma unroll
    for (int k = 0; k < 3; ++k) {
        float s = wave_sum(a[k]);
        if (lane == 0) red[k][wid] = s;
    }
    __syncthreads();
    if (t == 0) {
        float i_r = red[0][0] + red[0][1] + red[0][2] + red[0][3] + b_ih[r];
        float i_z = red[1][0] + red[1][1] + red[1][2] + red[1][3] + b_ih[HH + r];
        float i_n = red[2][0] + red[2][1] + red[2][2] + red[2][3] + b_ih[2 * HH + r];
        float h_r = gh[r];
        float h_z = gh[HH + r];
        float h_n = gh[2 * HH + r];
        float rg = 1.f / (1.f + expf(-(i_r + h_r)));
        float z  = 1.f / (1.f + expf(-(i_z + h_z)));
        float n  = tanhf(i_n + rg * h_n);
        h_new[r] = (1.f - z) * n + z * h[r];
    }
}

// out logits: block per row, L=4096; out_W stream-once (nt)
__global__ void k_out(const float* __restrict__ W, const float* __restrict__ xv,
                      const float* __restrict__ b, float* __restrict__ y) {
    int r = blockIdx.x;
    float acc = dot_row<4, true>((const f4*)(W + (size_t)r * HH), (const f4*)xv);
    float tot = block_sum(acc);
    if (threadIdx.x == 0) y[r] = tot + b[r];
}

// log_softmax over 4096: 16 blocks, each redundantly computes the stats
// (identical order -> identical lse) and writes its own 256-col slice.
__global__ void k_lsm(const float* __restrict__ l, float* __restrict__ out) {
    __shared__ float red[4];
    __shared__ float bval;
    int t = threadIdx.x;
    float v[16];
    float m = -INFINITY;
#pragma unroll
    for (int j = 0; j < 16; ++j) { v[j] = l[t + 256 * j]; m = fmaxf(m, v[j]); }
    m = wave_max(m);
    if ((t & 63) == 0) red[t >> 6] = m;
    __syncthreads();
    if (t == 0) bval = fmaxf(fmaxf(red[0], red[1]), fmaxf(red[2], red[3]));
    __syncthreads();
    float mx = bval;
    float s = 0.f;
#pragma unroll
    for (int j = 0; j < 16; ++j) s += expf(v[j] - mx);
    s = wave_sum(s);
    __syncthreads();
    if ((t & 63) == 0) red[t >> 6] = s;
    __syncthreads();
    if (t == 0) bval = red[0] + red[1] + red[2] + red[3];
    __syncthreads();
    float lse = mx + logf(bval);
    // thread t's value v[j] sits at index t + 256*j; block b owns j == b
    out[blockIdx.x * 256 + t] = v[blockIdx.x] - lse;
}

extern "C" void kernel_launch(void* const* d_in, const int* in_sizes, int n_in,
                              void* d_out, int out_size, void* d_ws, size_t ws_size,
                              hipStream_t stream) {
    const int*   idx     = (const int*)  d_in[0];
    const float* hidden  = (const float*)d_in[1];
    // d_in[2] (encoder_output) unused by the forward pass
    const float* enc     = (const float*)d_in[3];
    const float* emb_W   = (const float*)d_in[4];
    const float* att_W   = (const float*)d_in[5];
    const float* att_b   = (const float*)d_in[6];
    const float* atc_W   = (const float*)d_in[7];
    const float* atc_b   = (const float*)d_in[8];
    const float* W_ih    = (const float*)d_in[9];
    const float* W_hh    = (const float*)d_in[10];
    const float* b_ih    = (const float*)d_in[11];
    const float* b_hh    = (const float*)d_in[12];
    const float* out_W   = (const float*)d_in[13];
    const float* out_b   = (const float*)d_in[14];

    float* out    = (float*)d_out;        // [0, 4096)    log_softmax
    float* h_new  = out + OO;             // [4096, 8192) new hidden
    float* atw    = out + OO + HH;        // [8192,10240) attention weights

    float* ws         = (float*)d_ws;
    float* attlog     = ws;               // 2048
    float* atap       = ws + 2048;        // 4096
    float* x          = ws + 6144;        // 4096
    float* outlog     = ws + 10240;       // 4096
    float* gh         = ws + 14336;       // 12288
    float* part       = ws + 26624;       // 128*4096

    // 1. att logits + gh = W_hh@hidden + b_hh (fused, interleaved 7:1)
    k_stage1<<<MAXLEN + 3 * HH, 256, 0, stream>>>(att_W, att_b, emb_W, idx, hidden,
                                                  W_hh, b_hh, attlog, gh);
    // 2. fused softmax + weighted partial column-sums (also writes atw output)
    k_smpart<<<512, 256, 0, stream>>>(attlog, enc, part, atw);
    // 3. deterministic reduce -> atap
    k_red<<<16, 256, 0, stream>>>(part, atap);
    // 4. x = relu(atc_W @ [emb|atap] + atc_b)
    k_atc<<<HH, 256, 0, stream>>>(atc_W, atc_b, emb_W, idx, atap, x);
    // 5. gi + gate math -> h_new output
    k_gig<<<HH, 256, 0, stream>>>(W_ih, b_ih, x, gh, hidden, h_new);
    // 6. out logits (block per row)
    k_out<<<HH, 256, 0, stream>>>(out_W, h_new, out_b, outlog);
    // 7. log_softmax -> out (16 blocks, redundant stats)
    k_lsm<<<16, 256, 0, stream>>>(outlog, out);
}

// Round 9
// 121.832 us; speedup vs baseline: 4.8083x; 1.0558x over previous
//
#include <hip/hip_runtime.h>
#include <math.h>

#define HH 4096
#define OO 4096
#define MAXLEN 2048

typedef float f4 __attribute__((ext_vector_type(4)));

__device__ inline float wave_sum(float v) {
#pragma unroll
    for (int off = 32; off; off >>= 1) v += __shfl_down(v, off, 64);
    return v;
}
__device__ inline float wave_max(float v) {
#pragma unroll
    for (int off = 32; off; off >>= 1) v = fmaxf(v, __shfl_down(v, off, 64));
    return v;
}

// sum 256 per-thread partials; result valid in all threads
__device__ inline float block_sum(float acc) {
    __shared__ float red[4];
    acc = wave_sum(acc);
    int t = threadIdx.x;
    if ((t & 63) == 0) red[t >> 6] = acc;
    __syncthreads();
    return red[0] + red[1] + red[2] + red[3];
}

// per-thread partial dot over 1024*NV floats; 256 threads/block.
// NT: non-temporal (stream-once) hint on the W side only.
template <int NV, bool NT>
__device__ inline float dot_row(const f4* __restrict__ W4, const f4* __restrict__ x4) {
    int t = threadIdx.x;
    float acc = 0.f;
#pragma unroll
    for (int j = 0; j < NV; ++j) {
        f4 w = NT ? __builtin_nontemporal_load(W4 + t + 256 * j) : W4[t + 256 * j];
        f4 v = x4[t + 256 * j];
        acc = fmaf(w[0], v[0], acc);
        acc = fmaf(w[1], v[1], acc);
        acc = fmaf(w[2], v[2], acc);
        acc = fmaf(w[3], v[3], acc);
    }
    return acc;
}

// fused first stage, 18432 = 9*2048 blocks, interleaved 1:6:2 —
//   m==0   -> attention logit row k            (att_W nt, 2 passes)
//   m=1..6 -> gh row k*6+m-1 = W_hh·h + b_hh   (W_hh non-nt, L3-resident)
//   m=7..8 -> atcemb row k*2+m-7 = atc_W[r,:H]·emb + atc_b  (nt)
__global__ void k_stage1(const float* __restrict__ att_W, const float* __restrict__ att_b,
                         const float* __restrict__ emb_W, const int* __restrict__ idx,
                         const float* __restrict__ hidden,
                         const float* __restrict__ W_hh, const float* __restrict__ b_hh,
                         const float* __restrict__ atc_W, const float* __restrict__ atc_b,
                         float* __restrict__ attlog, float* __restrict__ gh,
                         float* __restrict__ atcemb) {
    int blk = blockIdx.x;
    int k = blk / 9, m = blk % 9;
    if (m == 0) {
        int r = k;                         // 0..2047
        const float* emb = emb_W + (size_t)idx[0] * HH;
        const float* Wr = att_W + (size_t)r * (2 * HH);
        float acc = dot_row<4, true>((const f4*)Wr, (const f4*)emb)
                  + dot_row<4, true>((const f4*)(Wr + HH), (const f4*)hidden);
        float tot = block_sum(acc);
        if (threadIdx.x == 0) attlog[r] = tot + att_b[r];
    } else if (m <= 6) {
        int r = k * 6 + (m - 1);           // 0..12287
        float acc = dot_row<4, false>((const f4*)(W_hh + (size_t)r * HH), (const f4*)hidden);
        float tot = block_sum(acc);
        if (threadIdx.x == 0) gh[r] = tot + b_hh[r];
    } else {
        int r = k * 2 + (m - 7);           // 0..4095
        const float* emb = emb_W + (size_t)idx[0] * HH;
        float acc = dot_row<4, true>((const f4*)(atc_W + (size_t)r * (2 * HH)), (const f4*)emb);
        float tot = block_sum(acc);
        if (threadIdx.x == 0) atcemb[r] = tot + atc_b[r];
    }
}

// fused softmax + weighted partial column-sums.
// 512 blocks = 128 row-chunks (16 rows) x 4 col-quarters. Each block
// redundantly computes softmax stats from attlog (8KB, cache-resident).
// q==0 blocks also write atw (the third output). enc NON-nt (L3-resident set).
__global__ void k_smpart(const float* __restrict__ attlog, const float* __restrict__ E,
                         float* __restrict__ part, float* __restrict__ atw) {
    __shared__ float red[4];
    __shared__ float s_mx, s_sum;
    int t = threadIdx.x;
    int q = blockIdx.x & 3;
    int c = blockIdx.x >> 2;              // 0..127

    float v[8];
    float m = -INFINITY;
#pragma unroll
    for (int j = 0; j < 8; ++j) { v[j] = attlog[t + 256 * j]; m = fmaxf(m, v[j]); }
    m = wave_max(m);
    if ((t & 63) == 0) red[t >> 6] = m;
    __syncthreads();
    if (t == 0) s_mx = fmaxf(fmaxf(red[0], red[1]), fmaxf(red[2], red[3]));
    __syncthreads();
    float mx = s_mx;
    float s = 0.f;
#pragma unroll
    for (int j = 0; j < 8; ++j) s += expf(v[j] - mx);
    s = wave_sum(s);
    __syncthreads();
    if ((t & 63) == 0) red[t >> 6] = s;
    __syncthreads();
    if (t == 0) s_sum = red[0] + red[1] + red[2] + red[3];
    __syncthreads();
    float inv = 1.0f / s_sum;

    int col4 = q * 256 + t;
    f4 acc = {0.f, 0.f, 0.f, 0.f};
#pragma unroll 8
    for (int rr = 0; rr < 16; ++rr) {
        int mrow = c * 16 + rr;
        float wm = expf(attlog[mrow] - mx) * inv;
        f4 e = ((const f4*)(E + (size_t)mrow * HH))[col4];
        acc[0] = fmaf(wm, e[0], acc[0]);
        acc[1] = fmaf(wm, e[1], acc[1]);
        acc[2] = fmaf(wm, e[2], acc[2]);
        acc[3] = fmaf(wm, e[3], acc[3]);
    }
    ((f4*)(part + (size_t)c * HH))[col4] = acc;

    if (q == 0 && t < 16) {
        int mrow = c * 16 + t;
        atw[mrow] = expf(attlog[mrow] - mx) * inv;
    }
}

// deterministic reduce of 128 partial rows -> atap.
// 32 blocks x 256 threads; 8 threads cooperate per f4 output (16 c's each,
// c = cp + 8*i ascending -> fixed order), in-wave shfl tree (width-8 groups).
__global__ void k_red(const float* __restrict__ part, float* __restrict__ atap) {
    int t = threadIdx.x;
    int o  = blockIdx.x * 32 + (t >> 3);   // f4 output index, 0..1023
    int cp = t & 7;
    f4 s = {0.f, 0.f, 0.f, 0.f};
#pragma unroll
    for (int i = 0; i < 16; ++i) {
        f4 p = ((const f4*)part)[(size_t)(cp + 8 * i) * (HH / 4) + o];
        s[0] += p[0]; s[1] += p[1]; s[2] += p[2]; s[3] += p[3];
    }
#pragma unroll
    for (int off = 4; off; off >>= 1) {
        s[0] += __shfl_down(s[0], off, 64);
        s[1] += __shfl_down(s[1], off, 64);
        s[2] += __shfl_down(s[2], off, 64);
        s[3] += __shfl_down(s[3], off, 64);
    }
    if (cp == 0) ((f4*)atap)[o] = s;
}

// x = relu(atcemb + atc_W[r, H:2H]·atap), block per row, 16KB/block (nt)
__global__ void k_atc2(const float* __restrict__ atc_W, const float* __restrict__ atcemb,
                       const float* __restrict__ atap, float* __restrict__ x) {
    int r = blockIdx.x;
    float acc = dot_row<4, true>((const f4*)(atc_W + (size_t)r * (2 * HH) + HH),
                                 (const f4*)atap);
    float tot = block_sum(acc);
    if (threadIdx.x == 0) x[r] = fmaxf(tot + atcemb[r], 0.f);
}

// gi + gate math: block r computes 3 W_ih row-dots vs x (nt), combines with
// precomputed gh (already includes b_hh) -> h_new[r].
__global__ void k_gig(const float* __restrict__ W_ih, const float* __restrict__ b_ih,
                      const float* __restrict__ x, const float* __restrict__ gh,
                      const float* __restrict__ h, float* __restrict__ h_new) {
    __shared__ float red[3][4];
    int r = blockIdx.x;
    int t = threadIdx.x, wid = t >> 6, lane = t & 63;
    const f4* xv = (const f4*)x;
    float a[3];
    a[0] = dot_row<4, true>((const f4*)(W_ih + (size_t)r * HH), xv);
    a[1] = dot_row<4, true>((const f4*)(W_ih + (size_t)(HH + r) * HH), xv);
    a[2] = dot_row<4, true>((const f4*)(W_ih + (size_t)(2 * HH + r) * HH), xv);
#pragma unroll
    for (int k = 0; k < 3; ++k) {
        float s = wave_sum(a[k]);
        if (lane == 0) red[k][wid] = s;
    }
    __syncthreads();
    if (t == 0) {
        float i_r = red[0][0] + red[0][1] + red[0][2] + red[0][3] + b_ih[r];
        float i_z = red[1][0] + red[1][1] + red[1][2] + red[1][3] + b_ih[HH + r];
        float i_n = red[2][0] + red[2][1] + red[2][2] + red[2][3] + b_ih[2 * HH + r];
        float h_r = gh[r];
        float h_z = gh[HH + r];
        float h_n = gh[2 * HH + r];
        float rg = 1.f / (1.f + expf(-(i_r + h_r)));
        float z  = 1.f / (1.f + expf(-(i_z + h_z)));
        float n  = tanhf(i_n + rg * h_n);
        h_new[r] = (1.f - z) * n + z * h[r];
    }
}

// out logits: block per row, L=4096; out_W stream-once (nt)
__global__ void k_out(const float* __restrict__ W, const float* __restrict__ xv,
                      const float* __restrict__ b, float* __restrict__ y) {
    int r = blockIdx.x;
    float acc = dot_row<4, true>((const f4*)(W + (size_t)r * HH), (const f4*)xv);
    float tot = block_sum(acc);
    if (threadIdx.x == 0) y[r] = tot + b[r];
}

// log_softmax over 4096: 16 blocks, each redundantly computes the stats
// (identical order -> identical lse) and writes its own 256-col slice.
__global__ void k_lsm(const float* __restrict__ l, float* __restrict__ out) {
    __shared__ float red[4];
    __shared__ float bval;
    int t = threadIdx.x;
    float v[16];
    float m = -INFINITY;
#pragma unroll
    for (int j = 0; j < 16; ++j) { v[j] = l[t + 256 * j]; m = fmaxf(m, v[j]); }
    m = wave_max(m);
    if ((t & 63) == 0) red[t >> 6] = m;
    __syncthreads();
    if (t == 0) bval = fmaxf(fmaxf(red[0], red[1]), fmaxf(red[2], red[3]));
    __syncthreads();
    float mx = bval;
    float s = 0.f;
#pragma unroll
    for (int j = 0; j < 16; ++j) s += expf(v[j] - mx);
    s = wave_sum(s);
    __syncthreads();
    if ((t & 63) == 0) red[t >> 6] = s;
    __syncthreads();
    if (t == 0) bval = red[0] + red[1] + red[2] + red[3];
    __syncthreads();
    float lse = mx + logf(bval);
    // thread t's value v[j] sits at index t + 256*j; block b owns j == b
    out[blockIdx.x * 256 + t] = v[blockIdx.x] - lse;
}

extern "C" void kernel_launch(void* const* d_in, const int* in_sizes, int n_in,
                              void* d_out, int out_size, void* d_ws, size_t ws_size,
                              hipStream_t stream) {
    const int*   idx     = (const int*)  d_in[0];
    const float* hidden  = (const float*)d_in[1];
    // d_in[2] (encoder_output) unused by the forward pass
    const float* enc     = (const float*)d_in[3];
    const float* emb_W   = (const float*)d_in[4];
    const float* att_W   = (const float*)d_in[5];
    const float* att_b   = (const float*)d_in[6];
    const float* atc_W   = (const float*)d_in[7];
    const float* atc_b   = (const float*)d_in[8];
    const float* W_ih    = (const float*)d_in[9];
    const float* W_hh    = (const float*)d_in[10];
    const float* b_ih    = (const float*)d_in[11];
    const float* b_hh    = (const float*)d_in[12];
    const float* out_W   = (const float*)d_in[13];
    const float* out_b   = (const float*)d_in[14];

    float* out    = (float*)d_out;        // [0, 4096)    log_softmax
    float* h_new  = out + OO;             // [4096, 8192) new hidden
    float* atw    = out + OO + HH;        // [8192,10240) attention weights

    float* ws         = (float*)d_ws;
    float* attlog     = ws;               // 2048
    float* atap       = ws + 2048;        // 4096
    float* x          = ws + 6144;        // 4096
    float* outlog     = ws + 10240;       // 4096
    float* gh         = ws + 14336;       // 12288
    float* atcemb     = ws + 26624;       // 4096
    float* part       = ws + 30720;       // 128*4096

    // 1. att logits + gh + atc emb-half (fused, 18432 blocks, 1:6:2 interleave)
    k_stage1<<<9 * MAXLEN, 256, 0, stream>>>(att_W, att_b, emb_W, idx, hidden,
                                             W_hh, b_hh, atc_W, atc_b,
                                             attlog, gh, atcemb);
    // 2. fused softmax + weighted partial column-sums (also writes atw output)
    k_smpart<<<512, 256, 0, stream>>>(attlog, enc, part, atw);
    // 3. deterministic wide reduce -> atap (f4 loads, 8 thr/output)
    k_red<<<32, 256, 0, stream>>>(part, atap);
    // 4. x = relu(atcemb + atc_W_right @ atap)
    k_atc2<<<HH, 256, 0, stream>>>(atc_W, atcemb, atap, x);
    // 5. gi + gate math -> h_new output
    k_gig<<<HH, 256, 0, stream>>>(W_ih, b_ih, x, gh, hidden, h_new);
    // 6. out logits (block per row)
    k_out<<<HH, 256, 0, stream>>>(out_W, h_new, out_b, outlog);
    // 7. log_softmax -> out (16 blocks, redundant stats)
    k_lsm<<<16, 256, 0, stream>>>(outlog, out);
}